// Round 1
// baseline (256.486 us; speedup 1.0000x reference)
//
#include <hip/hip_runtime.h>
#include <hip/hip_bf16.h>
#include <stdint.h>

#define B_TOTAL 131072

typedef __attribute__((ext_vector_type(8))) short short8;
typedef __attribute__((ext_vector_type(16))) float float16v;

// ws layout: bf16 region (uint16 indices), then f32 region (float indices)
#define oW1T 0          // [6][128 n][128 kpad] bf16, k>=100 zero
#define oW2T 98304      // [6][64 n][128 k]
#define oW3T 147456     // [6][32 n][64 k]
#define BF16_TOT 159744
#define F32_BASE 79872  // float index (159744 u16 = 319488 B = 79872 floats)
#define oB1 (F32_BASE)        // 768
#define oB2 (F32_BASE+768)    // 384
#define oB3 (F32_BASE+1152)   // 192
#define oW4f (F32_BASE+1344)  // 192
#define oB4 (F32_BASE+1536)   // 6
#define oCP (F32_BASE+1542)   // 36
#define oDC (F32_BASE+1578)   // 6
#define CONV_TOT (BF16_TOT+1584)

__device__ __forceinline__ float bf16_as_f32(uint16_t u) {
    union { uint32_t i; float f; } v; v.i = ((uint32_t)u) << 16; return v.f;
}
__device__ __forceinline__ uint16_t f2bf(float f) {
    uint32_t u = __float_as_uint(f);
    return (uint16_t)((u + 0x7FFFu + ((u >> 16) & 1u)) >> 16);   // RNE
}
__device__ __forceinline__ float sigmoidf_fast(float x) {
    return __builtin_amdgcn_rcpf(1.0f + __expf(-x));
}
__device__ __forceinline__ float siluf(float x) { return x * sigmoidf_fast(x); }

__device__ __forceinline__ float readsrc(const void* p, int off, bool bf) {
    return bf ? bf16_as_f32(((const uint16_t*)p)[off]) : ((const float*)p)[off];
}

// v_cvt_pk_bf16_f32: dst.lo = bf16(lo), dst.hi = bf16(hi), RNE — 1 instr for 2 elems.
__device__ __forceinline__ uint32_t cvtpk_bf16(float lo, float hi) {
    uint32_t r;
    asm("v_cvt_pk_bf16_f32 %0, %1, %2" : "=v"(r) : "v"(lo), "v"(hi));
    return r;
}
// v_permlane32_swap_b32 a,b:  a' = [a_lo | b_lo],  b' = [a_hi | b_hi]
__device__ __forceinline__ void plane32swap(uint32_t& a, uint32_t& b) {
    asm("v_permlane32_swap_b32 %0, %1" : "+v"(a), "+v"(b));
}

// Transposed bf16 weights (k-padded W1) + f32 smalls. (unchanged, known-good)
__global__ void convert_kernel(const void* W1, const void* b1, const void* W2, const void* b2,
                               const void* W3, const void* b3, const void* W4, const void* b4,
                               const void* cp, const void* dc, uint16_t* __restrict__ wsb) {
    const bool bf = (((const uint32_t*)cp)[0] != 0u);
    int idx = blockIdx.x * 256 + threadIdx.x;
    if (idx >= CONV_TOT) return;
    if (idx < BF16_TOT) {
        float v;
        if (idx < oW2T) {            // W1t[c][n][k(128)] <- W1[c][k][n], k>=100 -> 0
            int c = idx >> 14, r = idx & 16383, n = r >> 7, k = r & 127;
            v = (k < 100) ? readsrc(W1, c * 12800 + k * 128 + n, bf) : 0.0f;
        } else if (idx < oW3T) {     // W2t[c][n(64)][k(128)] <- W2[c][k][n]
            int j = idx - oW2T; int c = j >> 13, r = j & 8191, n = r >> 7, k = r & 127;
            v = readsrc(W2, c * 8192 + k * 64 + n, bf);
        } else {                     // W3t[c][n(32)][k(64)] <- W3[c][k][n]
            int j = idx - oW3T; int c = j >> 11, r = j & 2047, n = r >> 6, k = r & 63;
            v = readsrc(W3, c * 2048 + k * 32 + n, bf);
        }
        wsb[idx] = f2bf(v);
    } else {
        int fi = idx - BF16_TOT;
        float v;
        if      (fi < 768)  v = readsrc(b1, fi, bf);
        else if (fi < 1152) v = readsrc(b2, fi - 768, bf);
        else if (fi < 1344) v = readsrc(b3, fi - 1152, bf);
        else if (fi < 1536) v = readsrc(W4, fi - 1344, bf);
        else if (fi < 1542) v = readsrc(b4, fi - 1536, bf);
        else if (fi < 1578) v = readsrc(cp, fi - 1542, bf);
        else                v = readsrc(dc, fi - 1578, bf);
        ((float*)wsb)[F32_BASE + fi] = v;
    }
}

union Frag { uint4 u4; uint2 u2[2]; uint32_t u[4]; short8 s8; uint16_t h[8]; };

#define Z16 {0.f,0.f,0.f,0.f,0.f,0.f,0.f,0.f,0.f,0.f,0.f,0.f,0.f,0.f,0.f,0.f}

// Transposed-MFMA chain, 32x32x16, zero LDS / zero barriers.
// Each wave owns 32 batch rows for the whole kernel. Per MFMA: A = weights
// (Wt[n][k], n=lane&31, k=(lane>>5)*8+e), B = activations (act[r][k], r=lane&31).
// D = H^T tile: lane(q2,l5) holds H[r=l5][n = 32ct + 8*(reg>>2) + 4*q2 + (reg&3)].
// Packed pairs pk[a][m] (a = n>>3, m = (n>>1)&1) feed the next layer's B-frag:
// frag kb = {swap(pk[2kb][0],pk[2kb+1][0]) -> u0,u2 ; swap(...[1]) -> u1,u3}.
__global__ __launch_bounds__(256, 4)
void chambers_mfma(const void* __restrict__ resv, const uint16_t* __restrict__ wsb,
                   const uint32_t* __restrict__ cpw, float* __restrict__ outF) {
    const float* wsf = (const float*)wsb;
    const bool bfin = (cpw[0] != 0u);
    const int tid = threadIdx.x;
    const int w = tid >> 6, l = tid & 63;
    const int l5 = l & 31, q2 = l >> 5;
    const int row = blockIdx.x * 128 + w * 32 + l5;

    // ===== res row fragments (B operand), K padded 100 -> 112, converted ONCE =====
    Frag R[7];
    if (bfin) {
        const uint16_t* bp = (const uint16_t*)resv + (size_t)row * 100;
#pragma unroll
        for (int kb = 0; kb < 6; ++kb) {
            const int k0 = kb * 16 + q2 * 8;
            R[kb].u2[0] = *(const uint2*)(bp + k0);
            R[kb].u2[1] = *(const uint2*)(bp + k0 + 4);
        }
        R[6].u4 = make_uint4(0, 0, 0, 0);
        if (q2 == 0) R[6].u2[0] = *(const uint2*)(bp + 96);
    } else {
        const float* fp = (const float*)resv + (size_t)row * 100;
#pragma unroll
        for (int kb = 0; kb < 6; ++kb) {
            const int k0 = kb * 16 + q2 * 8;
            float4 x0 = *(const float4*)(fp + k0);
            float4 x1 = *(const float4*)(fp + k0 + 4);
            R[kb].u[0] = cvtpk_bf16(x0.x, x0.y);
            R[kb].u[1] = cvtpk_bf16(x0.z, x0.w);
            R[kb].u[2] = cvtpk_bf16(x1.x, x1.y);
            R[kb].u[3] = cvtpk_bf16(x1.z, x1.w);
        }
        R[6].u4 = make_uint4(0, 0, 0, 0);
        if (q2 == 0) {
            float4 x0 = *(const float4*)(fp + 96);
            R[6].u[0] = cvtpk_bf16(x0.x, x0.y);
            R[6].u[1] = cvtpk_bf16(x0.z, x0.w);
        }
    }

    float raw0 = 0.f, raw1 = 0.f, raw2 = 0.f, raw3 = 0.f, raw4 = 0.f, raw5 = 0.f;
    uint32_t pk1[16][2];   // H1 (n=128): static-indexed only -> registers
    uint32_t pk2[8][2];    // H2 (n=64)

#pragma unroll 1
    for (int c = 0; c < 6; ++c) {
        // ===== L1: H1^T = W1t . res^T   (4 col-tiles of 32, K=112) =====
#pragma unroll
        for (int ct = 0; ct < 4; ++ct) {
            float16v acc = Z16;
            const uint16_t* wp = wsb + oW1T + (size_t)(c * 128 + ct * 32 + l5) * 128 + q2 * 8;
#pragma unroll
            for (int kb = 0; kb < 7; ++kb) {
                Frag Af; Af.u4 = *(const uint4*)(wp + kb * 16);
                acc = __builtin_amdgcn_mfma_f32_32x32x16_bf16(Af.s8, R[kb].s8, acc, 0, 0, 0);
            }
#pragma unroll
            for (int ar = 0; ar < 4; ++ar) {
                const float4 bv = *(const float4*)(wsf + oB1 + c * 128 + ct * 32 + ar * 8 + q2 * 4);
                pk1[ct * 4 + ar][0] = cvtpk_bf16(siluf(acc[4 * ar + 0] + bv.x),
                                                 siluf(acc[4 * ar + 1] + bv.y));
                pk1[ct * 4 + ar][1] = cvtpk_bf16(siluf(acc[4 * ar + 2] + bv.z),
                                                 siluf(acc[4 * ar + 3] + bv.w));
            }
        }
        // ===== L2: H2^T = W2t . H1^T   (2 col-tiles, K=128) =====
#pragma unroll
        for (int ct2 = 0; ct2 < 2; ++ct2) {
            float16v acc = Z16;
            const uint16_t* wp = wsb + oW2T + (size_t)(c * 64 + ct2 * 32 + l5) * 128 + q2 * 8;
#pragma unroll
            for (int kb = 0; kb < 8; ++kb) {
                uint32_t x0 = pk1[2 * kb][0], y0 = pk1[2 * kb + 1][0];
                uint32_t x1 = pk1[2 * kb][1], y1 = pk1[2 * kb + 1][1];
                plane32swap(x0, y0);
                plane32swap(x1, y1);
                Frag Hf; Hf.u[0] = x0; Hf.u[1] = x1; Hf.u[2] = y0; Hf.u[3] = y1;
                Frag Af; Af.u4 = *(const uint4*)(wp + kb * 16);
                acc = __builtin_amdgcn_mfma_f32_32x32x16_bf16(Af.s8, Hf.s8, acc, 0, 0, 0);
            }
#pragma unroll
            for (int ar = 0; ar < 4; ++ar) {
                const float4 bv = *(const float4*)(wsf + oB2 + c * 64 + ct2 * 32 + ar * 8 + q2 * 4);
                pk2[ct2 * 4 + ar][0] = cvtpk_bf16(siluf(acc[4 * ar + 0] + bv.x),
                                                  siluf(acc[4 * ar + 1] + bv.y));
                pk2[ct2 * 4 + ar][1] = cvtpk_bf16(siluf(acc[4 * ar + 2] + bv.z),
                                                  siluf(acc[4 * ar + 3] + bv.w));
            }
        }
        // ===== L3: H3^T = W3t . H2^T   (1 col-tile of 32, K=64) =====
        {
            float16v acc = Z16;
            const uint16_t* wp = wsb + oW3T + (size_t)(c * 32 + l5) * 64 + q2 * 8;
#pragma unroll
            for (int kb = 0; kb < 4; ++kb) {
                uint32_t x0 = pk2[2 * kb][0], y0 = pk2[2 * kb + 1][0];
                uint32_t x1 = pk2[2 * kb][1], y1 = pk2[2 * kb + 1][1];
                plane32swap(x0, y0);
                plane32swap(x1, y1);
                Frag Hf; Hf.u[0] = x0; Hf.u[1] = x1; Hf.u[2] = y0; Hf.u[3] = y1;
                Frag Af; Af.u4 = *(const uint4*)(wp + kb * 16);
                acc = __builtin_amdgcn_mfma_f32_32x32x16_bf16(Af.s8, Hf.s8, acc, 0, 0, 0);
            }
            // ===== L4 in-register: raw[r=l5] = silu(H3).W4 + b4, reduce over q2 =====
            float part = 0.f;
#pragma unroll
            for (int ar = 0; ar < 4; ++ar) {
                const float4 bv = *(const float4*)(wsf + oB3 + c * 32 + ar * 8 + q2 * 4);
                const float4 wv = *(const float4*)(wsf + oW4f + c * 32 + ar * 8 + q2 * 4);
                part = fmaf(siluf(acc[4 * ar + 0] + bv.x), wv.x, part);
                part = fmaf(siluf(acc[4 * ar + 1] + bv.y), wv.y, part);
                part = fmaf(siluf(acc[4 * ar + 2] + bv.z), wv.z, part);
                part = fmaf(siluf(acc[4 * ar + 3] + bv.w), wv.w, part);
            }
            part += __shfl_xor(part, 32);
            const float rv = part + wsf[oB4 + c];
            raw0 = (c == 0) ? rv : raw0;
            raw1 = (c == 1) ? rv : raw1;
            raw2 = (c == 2) ? rv : raw2;
            raw3 = (c == 3) ? rv : raw3;
            raw4 = (c == 4) ? rv : raw4;
            raw5 = (c == 5) ? rv : raw5;
        }
    }

    // ===== Coupling fixed point (all lanes redundant over q2; static indexing) =====
    const float rv6[6] = {raw0, raw1, raw2, raw3, raw4, raw5};
    float av[6];
#pragma unroll
    for (int c = 0; c < 6; ++c) av[c] = sigmoidf_fast(rv6[c]);
    const float K = 0.02f;
#pragma unroll 1
    for (int it = 0; it < 5; ++it) {
        float tt[6];
#pragma unroll
        for (int i = 0; i < 6; ++i) tt[i] = av[i] * wsf[oDC + i] * K;
#pragma unroll
        for (int j = 0; j < 6; ++j) {
            float dl = 0.0f;
#pragma unroll
            for (int i = 0; i < 6; ++i) dl = fmaf(tt[i], wsf[oCP + i * 6 + j], dl);
            av[j] = sigmoidf_fast(rv6[j] + dl);
        }
    }
    if (q2 == 0) {
        float2* oa = (float2*)(outF + (size_t)row * 6);
        oa[0] = make_float2(av[0], av[1]);
        oa[1] = make_float2(av[2], av[3]);
        oa[2] = make_float2(av[4], av[5]);
        float2* orw = (float2*)(outF + (size_t)B_TOTAL * 6 + (size_t)row * 6);
        orw[0] = make_float2(rv6[0], rv6[1]);
        orw[1] = make_float2(rv6[2], rv6[3]);
        orw[2] = make_float2(rv6[4], rv6[5]);
    }
}

extern "C" void kernel_launch(void* const* d_in, const int* in_sizes, int n_in,
                              void* d_out, int out_size, void* d_ws, size_t ws_size,
                              hipStream_t stream) {
    uint16_t* wsb = (uint16_t*)d_ws;
    convert_kernel<<<(CONV_TOT + 255) / 256, 256, 0, stream>>>(
        d_in[1], d_in[2], d_in[3], d_in[4], d_in[5], d_in[6], d_in[7], d_in[8],
        d_in[9], d_in[10], wsb);
    chambers_mfma<<<B_TOTAL / 128, 256, 0, stream>>>(
        d_in[0], wsb, (const uint32_t*)d_in[9], (float*)d_out);
}

// Round 2
// 163.549 us; speedup vs baseline: 1.5683x; 1.5683x over previous
//
#include <hip/hip_runtime.h>
#include <hip/hip_bf16.h>
#include <stdint.h>

#define B_TOTAL 131072

typedef __attribute__((ext_vector_type(8))) short short8;
typedef __attribute__((ext_vector_type(16))) float float16v;

// ===== fragment-linear ws layout =====
// Per chamber (u16 units):
//   F1: 28 frags (ct*7+kb) x 64 lanes x 8 bf16   -> 14336 u16 (28 KB)
//   F2: 16 frags (ct2*8+kb) x 64 x 8             ->  8192 u16 (16 KB)
//   F3:  4 frags (kb)       x 64 x 8             ->  2048 u16 ( 4 KB)
#define CH_U16 24576
#define oF2 14336
#define oF3 22528
#define BF16_TOT (6 * CH_U16)          // 147456 u16
#define F32_BASE (BF16_TOT / 2)        // 73728 floats
// f32 smalls, element offsets (also used inside sB):
#define sB1 0
#define sB2 768
#define sB3 1152
#define sW4 1344
#define sB4 1536
#define sCP 1542
#define sDC 1578
#define NSMALL 1584
#define CONV_TOT (BF16_TOT + NSMALL)

#define GLB_AS __attribute__((address_space(1)))
#define LDS_AS __attribute__((address_space(3)))

__device__ __forceinline__ float bf16_as_f32(uint16_t u) {
    union { uint32_t i; float f; } v; v.i = ((uint32_t)u) << 16; return v.f;
}
__device__ __forceinline__ uint16_t f2bf(float f) {
    uint32_t u = __float_as_uint(f);
    return (uint16_t)((u + 0x7FFFu + ((u >> 16) & 1u)) >> 16);   // RNE
}
__device__ __forceinline__ float sigmoidf_fast(float x) {
    return __builtin_amdgcn_rcpf(1.0f + __expf(-x));
}
__device__ __forceinline__ float siluf(float x) { return x * sigmoidf_fast(x); }

__device__ __forceinline__ float readsrc(const void* p, int off, bool bf) {
    return bf ? bf16_as_f32(((const uint16_t*)p)[off]) : ((const float*)p)[off];
}

__device__ __forceinline__ uint32_t cvtpk_bf16(float lo, float hi) {
    uint32_t r;
    asm("v_cvt_pk_bf16_f32 %0, %1, %2" : "=v"(r) : "v"(lo), "v"(hi));
    return r;
}
__device__ __forceinline__ void plane32swap(uint32_t& a, uint32_t& b) {
    asm("v_permlane32_swap_b32 %0, %1" : "+v"(a), "+v"(b));
}

// Fragment-linear bf16 weights + f32 smalls.
// Fragment (f, lane l, elem e): n-index uses (l&31), k-index uses (l>>5)*8+e.
__global__ void convert_kernel(const void* W1, const void* b1, const void* W2, const void* b2,
                               const void* W3, const void* b3, const void* W4, const void* b4,
                               const void* cp, const void* dc, uint16_t* __restrict__ wsb) {
    const bool bf = (((const uint32_t*)cp)[0] != 0u);
    int idx = blockIdx.x * 256 + threadIdx.x;
    if (idx >= CONV_TOT) return;
    if (idx < BF16_TOT) {
        int c = idx / CH_U16;
        int r = idx - c * CH_U16;
        float v;
        if (r < oF2) {                       // F1: W1t frag, K padded 100->112
            int f = r >> 9, rem = r & 511, l = rem >> 3, e = rem & 7;
            int ct = f / 7, kb = f - ct * 7;
            int n = ct * 32 + (l & 31), k = kb * 16 + (l >> 5) * 8 + e;
            v = (k < 100) ? readsrc(W1, c * 12800 + k * 128 + n, bf) : 0.0f;
        } else if (r < oF3) {                // F2: W2t frag
            int j = r - oF2;
            int f = j >> 9, rem = j & 511, l = rem >> 3, e = rem & 7;
            int ct2 = f >> 3, kb = f & 7;
            int n = ct2 * 32 + (l & 31), k = kb * 16 + (l >> 5) * 8 + e;
            v = readsrc(W2, c * 8192 + k * 64 + n, bf);
        } else {                             // F3: W3t frag
            int j = r - oF3;
            int kb = j >> 9, rem = j & 511, l = rem >> 3, e = rem & 7;
            int n = (l & 31), k = kb * 16 + (l >> 5) * 8 + e;
            v = readsrc(W3, c * 2048 + k * 32 + n, bf);
        }
        wsb[idx] = f2bf(v);
    } else {
        int fi = idx - BF16_TOT;
        float v;
        if      (fi < sB2)  v = readsrc(b1, fi, bf);
        else if (fi < sB3)  v = readsrc(b2, fi - sB2, bf);
        else if (fi < sW4)  v = readsrc(b3, fi - sB3, bf);
        else if (fi < sB4)  v = readsrc(W4, fi - sW4, bf);
        else if (fi < sCP)  v = readsrc(b4, fi - sB4, bf);
        else if (fi < sDC)  v = readsrc(cp, fi - sCP, bf);
        else                v = readsrc(dc, fi - sDC, bf);
        ((float*)wsb)[F32_BASE + fi] = v;
    }
}

union Frag { uint4 u4; uint2 u2[2]; uint32_t u[4]; short8 s8; uint16_t h[8]; };

#define Z16 {0.f,0.f,0.f,0.f,0.f,0.f,0.f,0.f,0.f,0.f,0.f,0.f,0.f,0.f,0.f,0.f}

// Transposed-MFMA chain (32x32x16): A = weight fragments (from LDS, staged per
// chamber via global_load_lds, lane-linear so ds_read_b128 is conflict-free),
// B = activations held in registers; inter-layer transpose via permlane32_swap.
// 512 threads = 8 waves x 32 rows = 256 rows/block; 2 blocks/CU (55.5 KB LDS).
__global__ __launch_bounds__(512, 4)
void chambers_mfma(const void* __restrict__ resv, const uint16_t* __restrict__ wsb,
                   const uint32_t* __restrict__ cpw, float* __restrict__ outF) {
    const float* wsf = (const float*)wsb;
    const bool bfin = (cpw[0] != 0u);
    const int tid = threadIdx.x;
    const int w = tid >> 6, l = tid & 63;
    const int l5 = l & 31, q2 = l >> 5;
    const int row = blockIdx.x * 256 + w * 32 + l5;

    __shared__ __align__(16) uint16_t sW[CH_U16];  // 49152 B, one chamber's fragments
    __shared__ __align__(16) float sB[NSMALL];     // 6336 B, all biases/consts

    // stage f32 smalls once
    for (int i = tid; i < NSMALL; i += 512) sB[i] = wsf[F32_BASE + i];

    // ===== res row fragments (B operand), K padded 100 -> 112, converted ONCE =====
    Frag R[7];
    if (bfin) {
        const uint16_t* bp = (const uint16_t*)resv + (size_t)row * 100;
#pragma unroll
        for (int kb = 0; kb < 6; ++kb) {
            const int k0 = kb * 16 + q2 * 8;
            R[kb].u2[0] = *(const uint2*)(bp + k0);
            R[kb].u2[1] = *(const uint2*)(bp + k0 + 4);
        }
        R[6].u4 = make_uint4(0, 0, 0, 0);
        if (q2 == 0) R[6].u2[0] = *(const uint2*)(bp + 96);
    } else {
        const float* fp = (const float*)resv + (size_t)row * 100;
#pragma unroll
        for (int kb = 0; kb < 6; ++kb) {
            const int k0 = kb * 16 + q2 * 8;
            float4 x0 = *(const float4*)(fp + k0);
            float4 x1 = *(const float4*)(fp + k0 + 4);
            R[kb].u[0] = cvtpk_bf16(x0.x, x0.y);
            R[kb].u[1] = cvtpk_bf16(x0.z, x0.w);
            R[kb].u[2] = cvtpk_bf16(x1.x, x1.y);
            R[kb].u[3] = cvtpk_bf16(x1.z, x1.w);
        }
        R[6].u4 = make_uint4(0, 0, 0, 0);
        if (q2 == 0) {
            float4 x0 = *(const float4*)(fp + 96);
            R[6].u[0] = cvtpk_bf16(x0.x, x0.y);
            R[6].u[1] = cvtpk_bf16(x0.z, x0.w);
        }
    }

    float raw0 = 0.f, raw1 = 0.f, raw2 = 0.f, raw3 = 0.f, raw4 = 0.f, raw5 = 0.f;
    uint32_t pk1[16][2];   // H1 (n=128): static-indexed only -> registers
    uint32_t pk2[8][2];    // H2 (n=64)

#pragma unroll 1
    for (int c = 0; c < 6; ++c) {
        if (c) __syncthreads();     // all waves done reading sW for chamber c-1
        // ===== stage chamber c fragments: 49152 B, 8 waves x 6 x 1 KB =====
        {
            const uint16_t* gsrc = wsb + c * CH_U16;
#pragma unroll
            for (int r = 0; r < 6; ++r) {
                const int chunk = r * 8 + w;              // 0..47, 1 KB each
                __builtin_amdgcn_global_load_lds(
                    (const GLB_AS uint32_t*)(gsrc + chunk * 512 + l * 8),
                    (LDS_AS uint32_t*)(sW + chunk * 512),
                    16, 0, 0);
            }
        }
        __syncthreads();            // staging (and sB on c==0) complete

        // ===== L1: H1^T = W1 . res^T   (4 col-tiles of 32, K=112) =====
#pragma unroll
        for (int ct = 0; ct < 4; ++ct) {
            float16v acc = Z16;
#pragma unroll
            for (int kb = 0; kb < 7; ++kb) {
                Frag Af; Af.u4 = *(const uint4*)(sW + ((ct * 7 + kb) * 64 + l) * 8);
                acc = __builtin_amdgcn_mfma_f32_32x32x16_bf16(Af.s8, R[kb].s8, acc, 0, 0, 0);
            }
#pragma unroll
            for (int ar = 0; ar < 4; ++ar) {
                const float4 bv = *(const float4*)(sB + sB1 + c * 128 + ct * 32 + ar * 8 + q2 * 4);
                pk1[ct * 4 + ar][0] = cvtpk_bf16(siluf(acc[4 * ar + 0] + bv.x),
                                                 siluf(acc[4 * ar + 1] + bv.y));
                pk1[ct * 4 + ar][1] = cvtpk_bf16(siluf(acc[4 * ar + 2] + bv.z),
                                                 siluf(acc[4 * ar + 3] + bv.w));
            }
        }
        // ===== L2: H2^T = W2 . H1^T   (2 col-tiles, K=128) =====
#pragma unroll
        for (int ct2 = 0; ct2 < 2; ++ct2) {
            float16v acc = Z16;
#pragma unroll
            for (int kb = 0; kb < 8; ++kb) {
                uint32_t x0 = pk1[2 * kb][0], y0 = pk1[2 * kb + 1][0];
                uint32_t x1 = pk1[2 * kb][1], y1 = pk1[2 * kb + 1][1];
                plane32swap(x0, y0);
                plane32swap(x1, y1);
                Frag Hf; Hf.u[0] = x0; Hf.u[1] = x1; Hf.u[2] = y0; Hf.u[3] = y1;
                Frag Af; Af.u4 = *(const uint4*)(sW + oF2 + ((ct2 * 8 + kb) * 64 + l) * 8);
                acc = __builtin_amdgcn_mfma_f32_32x32x16_bf16(Af.s8, Hf.s8, acc, 0, 0, 0);
            }
#pragma unroll
            for (int ar = 0; ar < 4; ++ar) {
                const float4 bv = *(const float4*)(sB + sB2 + c * 64 + ct2 * 32 + ar * 8 + q2 * 4);
                pk2[ct2 * 4 + ar][0] = cvtpk_bf16(siluf(acc[4 * ar + 0] + bv.x),
                                                  siluf(acc[4 * ar + 1] + bv.y));
                pk2[ct2 * 4 + ar][1] = cvtpk_bf16(siluf(acc[4 * ar + 2] + bv.z),
                                                  siluf(acc[4 * ar + 3] + bv.w));
            }
        }
        // ===== L3: H3^T = W3 . H2^T   (1 col-tile of 32, K=64) =====
        {
            float16v acc = Z16;
#pragma unroll
            for (int kb = 0; kb < 4; ++kb) {
                uint32_t x0 = pk2[2 * kb][0], y0 = pk2[2 * kb + 1][0];
                uint32_t x1 = pk2[2 * kb][1], y1 = pk2[2 * kb + 1][1];
                plane32swap(x0, y0);
                plane32swap(x1, y1);
                Frag Hf; Hf.u[0] = x0; Hf.u[1] = x1; Hf.u[2] = y0; Hf.u[3] = y1;
                Frag Af; Af.u4 = *(const uint4*)(sW + oF3 + (kb * 64 + l) * 8);
                acc = __builtin_amdgcn_mfma_f32_32x32x16_bf16(Af.s8, Hf.s8, acc, 0, 0, 0);
            }
            // ===== L4: raw[r=l5] = silu(H3).W4 + b4, reduce over q2 =====
            float part = 0.f;
#pragma unroll
            for (int ar = 0; ar < 4; ++ar) {
                const float4 bv = *(const float4*)(sB + sB3 + c * 32 + ar * 8 + q2 * 4);
                const float4 wv = *(const float4*)(sB + sW4 + c * 32 + ar * 8 + q2 * 4);
                part = fmaf(siluf(acc[4 * ar + 0] + bv.x), wv.x, part);
                part = fmaf(siluf(acc[4 * ar + 1] + bv.y), wv.y, part);
                part = fmaf(siluf(acc[4 * ar + 2] + bv.z), wv.z, part);
                part = fmaf(siluf(acc[4 * ar + 3] + bv.w), wv.w, part);
            }
            part += __shfl_xor(part, 32);
            const float rv = part + sB[sB4 + c];
            raw0 = (c == 0) ? rv : raw0;
            raw1 = (c == 1) ? rv : raw1;
            raw2 = (c == 2) ? rv : raw2;
            raw3 = (c == 3) ? rv : raw3;
            raw4 = (c == 4) ? rv : raw4;
            raw5 = (c == 5) ? rv : raw5;
        }
    }

    // ===== Coupling fixed point (redundant over q2; static indexing) =====
    const float rv6[6] = {raw0, raw1, raw2, raw3, raw4, raw5};
    float av[6];
#pragma unroll
    for (int c = 0; c < 6; ++c) av[c] = sigmoidf_fast(rv6[c]);
    const float K = 0.02f;
#pragma unroll 1
    for (int it = 0; it < 5; ++it) {
        float tt[6];
#pragma unroll
        for (int i = 0; i < 6; ++i) tt[i] = av[i] * sB[sDC + i] * K;
#pragma unroll
        for (int j = 0; j < 6; ++j) {
            float dl = 0.0f;
#pragma unroll
            for (int i = 0; i < 6; ++i) dl = fmaf(tt[i], sB[sCP + i * 6 + j], dl);
            av[j] = sigmoidf_fast(rv6[j] + dl);
        }
    }
    if (q2 == 0) {
        float2* oa = (float2*)(outF + (size_t)row * 6);
        oa[0] = make_float2(av[0], av[1]);
        oa[1] = make_float2(av[2], av[3]);
        oa[2] = make_float2(av[4], av[5]);
        float2* orw = (float2*)(outF + (size_t)B_TOTAL * 6 + (size_t)row * 6);
        orw[0] = make_float2(rv6[0], rv6[1]);
        orw[1] = make_float2(rv6[2], rv6[3]);
        orw[2] = make_float2(rv6[4], rv6[5]);
    }
}

extern "C" void kernel_launch(void* const* d_in, const int* in_sizes, int n_in,
                              void* d_out, int out_size, void* d_ws, size_t ws_size,
                              hipStream_t stream) {
    uint16_t* wsb = (uint16_t*)d_ws;
    convert_kernel<<<(CONV_TOT + 255) / 256, 256, 0, stream>>>(
        d_in[1], d_in[2], d_in[3], d_in[4], d_in[5], d_in[6], d_in[7], d_in[8],
        d_in[9], d_in[10], wsb);
    chambers_mfma<<<B_TOTAL / 256, 512, 0, stream>>>(
        d_in[0], wsb, (const uint32_t*)d_in[9], (float*)d_out);
}

// Round 3
// 161.395 us; speedup vs baseline: 1.5892x; 1.0133x over previous
//
#include <hip/hip_runtime.h>
#include <hip/hip_bf16.h>
#include <stdint.h>

#define B_TOTAL 131072

typedef __attribute__((ext_vector_type(8))) short short8;
typedef __attribute__((ext_vector_type(16))) float float16v;

// ===== fragment-linear ws layout =====
// Per chamber (u16 units):
//   F1: 28 frags (ct*7+kb) x 64 lanes x 8 bf16   -> 14336 u16 (28 KB)
//   F2: 16 frags (ct2*8+kb) x 64 x 8             ->  8192 u16 (16 KB)
//   F3:  4 frags (kb)       x 64 x 8             ->  2048 u16 ( 4 KB)
#define CH_U16 24576
#define oF2 14336
#define oF3 22528
#define BF16_TOT (6 * CH_U16)          // 147456 u16
#define F32_BASE (BF16_TOT / 2)        // 73728 floats
// f32 smalls, element offsets (also used inside sB):
#define sB1 0
#define sB2 768
#define sB3 1152
#define sW4 1344
#define sB4 1536
#define sCP 1542
#define sDC 1578
#define NSMALL 1584
#define CONV_TOT (BF16_TOT + NSMALL)

// LDS-resident weight region: F1 (28 KB) + F3 (4 KB) = 16384 u16
#define sWF3 14336

#define GLB_AS __attribute__((address_space(1)))
#define LDS_AS __attribute__((address_space(3)))

__device__ __forceinline__ float bf16_as_f32(uint16_t u) {
    union { uint32_t i; float f; } v; v.i = ((uint32_t)u) << 16; return v.f;
}
__device__ __forceinline__ uint16_t f2bf(float f) {
    uint32_t u = __float_as_uint(f);
    return (uint16_t)((u + 0x7FFFu + ((u >> 16) & 1u)) >> 16);   // RNE
}
__device__ __forceinline__ float sigmoidf_fast(float x) {
    return __builtin_amdgcn_rcpf(1.0f + __expf(-x));
}
__device__ __forceinline__ float siluf(float x) { return x * sigmoidf_fast(x); }

__device__ __forceinline__ float readsrc(const void* p, int off, bool bf) {
    return bf ? bf16_as_f32(((const uint16_t*)p)[off]) : ((const float*)p)[off];
}

__device__ __forceinline__ uint32_t cvtpk_bf16(float lo, float hi) {
    uint32_t r;
    asm("v_cvt_pk_bf16_f32 %0, %1, %2" : "=v"(r) : "v"(lo), "v"(hi));
    return r;
}
__device__ __forceinline__ void plane32swap(uint32_t& a, uint32_t& b) {
    asm("v_permlane32_swap_b32 %0, %1" : "+v"(a), "+v"(b));
}

// Fragment-linear bf16 weights + f32 smalls. (unchanged from round 2)
// Fragment (f, lane l, elem e): n-index uses (l&31), k-index uses (l>>5)*8+e.
__global__ void convert_kernel(const void* W1, const void* b1, const void* W2, const void* b2,
                               const void* W3, const void* b3, const void* W4, const void* b4,
                               const void* cp, const void* dc, uint16_t* __restrict__ wsb) {
    const bool bf = (((const uint32_t*)cp)[0] != 0u);
    int idx = blockIdx.x * 256 + threadIdx.x;
    if (idx >= CONV_TOT) return;
    if (idx < BF16_TOT) {
        int c = idx / CH_U16;
        int r = idx - c * CH_U16;
        float v;
        if (r < oF2) {                       // F1: W1t frag, K padded 100->112
            int f = r >> 9, rem = r & 511, l = rem >> 3, e = rem & 7;
            int ct = f / 7, kb = f - ct * 7;
            int n = ct * 32 + (l & 31), k = kb * 16 + (l >> 5) * 8 + e;
            v = (k < 100) ? readsrc(W1, c * 12800 + k * 128 + n, bf) : 0.0f;
        } else if (r < oF3) {                // F2: W2t frag
            int j = r - oF2;
            int f = j >> 9, rem = j & 511, l = rem >> 3, e = rem & 7;
            int ct2 = f >> 3, kb = f & 7;
            int n = ct2 * 32 + (l & 31), k = kb * 16 + (l >> 5) * 8 + e;
            v = readsrc(W2, c * 8192 + k * 64 + n, bf);
        } else {                             // F3: W3t frag
            int j = r - oF3;
            int kb = j >> 9, rem = j & 511, l = rem >> 3, e = rem & 7;
            int n = (l & 31), k = kb * 16 + (l >> 5) * 8 + e;
            v = readsrc(W3, c * 2048 + k * 32 + n, bf);
        }
        wsb[idx] = f2bf(v);
    } else {
        int fi = idx - BF16_TOT;
        float v;
        if      (fi < sB2)  v = readsrc(b1, fi, bf);
        else if (fi < sB3)  v = readsrc(b2, fi - sB2, bf);
        else if (fi < sW4)  v = readsrc(b3, fi - sB3, bf);
        else if (fi < sB4)  v = readsrc(W4, fi - sW4, bf);
        else if (fi < sCP)  v = readsrc(b4, fi - sB4, bf);
        else if (fi < sDC)  v = readsrc(cp, fi - sCP, bf);
        else                v = readsrc(dc, fi - sDC, bf);
        ((float*)wsb)[F32_BASE + fi] = v;
    }
}

union Frag { uint4 u4; uint2 u2[2]; uint32_t u[4]; short8 s8; uint16_t h[8]; };

// Transposed-MFMA chain (32x32x16). F1/F3 weights staged in LDS via
// global_load_lds (lane-linear); F2 weights prefetched per-wave into registers
// from global (L2-hot, issue-early so latency hides under L1/L2 compute).
// Biases folded into the MFMA accumulator init (C-in = bias).
// 512 threads = 8 waves x 32 rows = 256 rows/block.
__global__ __launch_bounds__(512, 4)
void chambers_mfma(const void* __restrict__ resv, const uint16_t* __restrict__ wsb,
                   const uint32_t* __restrict__ cpw, float* __restrict__ outF) {
    const float* wsf = (const float*)wsb;
    const bool bfin = (cpw[0] != 0u);
    const int tid = threadIdx.x;
    const int w = tid >> 6, l = tid & 63;
    const int l5 = l & 31, q2 = l >> 5;
    const int row = blockIdx.x * 256 + w * 32 + l5;

    __shared__ __align__(16) uint16_t sW[16384];   // 32 KB: F1 (28 KB) + F3 (4 KB)
    __shared__ __align__(16) float sB[NSMALL];     // 6336 B, all biases/consts

    // stage f32 smalls once
    for (int i = tid; i < NSMALL; i += 512) sB[i] = wsf[F32_BASE + i];

    // ===== res row fragments (B operand), K padded 100 -> 112, converted ONCE =====
    Frag R[7];
    if (bfin) {
        const uint16_t* bp = (const uint16_t*)resv + (size_t)row * 100;
#pragma unroll
        for (int kb = 0; kb < 6; ++kb) {
            const int k0 = kb * 16 + q2 * 8;
            R[kb].u2[0] = *(const uint2*)(bp + k0);
            R[kb].u2[1] = *(const uint2*)(bp + k0 + 4);
        }
        R[6].u4 = make_uint4(0, 0, 0, 0);
        if (q2 == 0) R[6].u2[0] = *(const uint2*)(bp + 96);
    } else {
        const float* fp = (const float*)resv + (size_t)row * 100;
#pragma unroll
        for (int kb = 0; kb < 6; ++kb) {
            const int k0 = kb * 16 + q2 * 8;
            float4 x0 = *(const float4*)(fp + k0);
            float4 x1 = *(const float4*)(fp + k0 + 4);
            R[kb].u[0] = cvtpk_bf16(x0.x, x0.y);
            R[kb].u[1] = cvtpk_bf16(x0.z, x0.w);
            R[kb].u[2] = cvtpk_bf16(x1.x, x1.y);
            R[kb].u[3] = cvtpk_bf16(x1.z, x1.w);
        }
        R[6].u4 = make_uint4(0, 0, 0, 0);
        if (q2 == 0) {
            float4 x0 = *(const float4*)(fp + 96);
            R[6].u[0] = cvtpk_bf16(x0.x, x0.y);
            R[6].u[1] = cvtpk_bf16(x0.z, x0.w);
        }
    }

    float raw0 = 0.f, raw1 = 0.f, raw2 = 0.f, raw3 = 0.f, raw4 = 0.f, raw5 = 0.f;
    uint32_t pk1[16][2];   // H1 (n=128): static-indexed only -> registers
    uint32_t pk2[8][2];    // H2 (n=64)

#pragma unroll 1
    for (int c = 0; c < 6; ++c) {
        if (c) __syncthreads();     // all waves done reading sW for chamber c-1
        // ===== stage F1+F3: 32 chunks of 1 KB, 4 per wave =====
        {
            const uint16_t* gsrc = wsb + c * CH_U16;
#pragma unroll
            for (int r = 0; r < 4; ++r) {
                const int i = r * 8 + w;               // LDS chunk 0..31
                const int gi = (i < 28) ? i : (i + 16);  // global chunk (F3 at 44..47)
                __builtin_amdgcn_global_load_lds(
                    (const GLB_AS uint32_t*)(gsrc + gi * 512 + l * 8),
                    (LDS_AS uint32_t*)(sW + i * 512),
                    16, 0, 0);
            }
        }
        __syncthreads();            // staging (and sB on c==0) complete

        // ---- issue F2 ct2=0 prefetch (latency hides under L1) ----
        const uint16_t* gF2 = wsb + c * CH_U16 + oF2;
        Frag F2a[8];
#pragma unroll
        for (int kb = 0; kb < 8; ++kb)
            F2a[kb].u4 = *(const uint4*)(gF2 + (kb * 64 + l) * 8);

        // ===== L1: H1^T = W1 . res^T   (4 col-tiles of 32, K=112) =====
#pragma unroll
        for (int ct = 0; ct < 4; ++ct) {
            float16v acc;
#pragma unroll
            for (int ar = 0; ar < 4; ++ar) {           // bias-fold: C-in = b1
                const float4 bv = *(const float4*)(sB + sB1 + c * 128 + ct * 32 + ar * 8 + q2 * 4);
                acc[4 * ar + 0] = bv.x; acc[4 * ar + 1] = bv.y;
                acc[4 * ar + 2] = bv.z; acc[4 * ar + 3] = bv.w;
            }
#pragma unroll
            for (int kb = 0; kb < 7; ++kb) {
                Frag Af; Af.u4 = *(const uint4*)(sW + ((ct * 7 + kb) * 64 + l) * 8);
                acc = __builtin_amdgcn_mfma_f32_32x32x16_bf16(Af.s8, R[kb].s8, acc, 0, 0, 0);
            }
#pragma unroll
            for (int ar = 0; ar < 4; ++ar) {
                pk1[ct * 4 + ar][0] = cvtpk_bf16(siluf(acc[4 * ar + 0]),
                                                 siluf(acc[4 * ar + 1]));
                pk1[ct * 4 + ar][1] = cvtpk_bf16(siluf(acc[4 * ar + 2]),
                                                 siluf(acc[4 * ar + 3]));
            }
        }

        // ---- issue F2 ct2=1 prefetch (hides under L2 ct2=0) ----
        Frag F2b[8];
#pragma unroll
        for (int kb = 0; kb < 8; ++kb)
            F2b[kb].u4 = *(const uint4*)(gF2 + ((8 + kb) * 64 + l) * 8);

        // ===== L2: H2^T = W2 . H1^T   (2 col-tiles, K=128; F2 from registers) =====
#define L2_TILE(F2R, CT2)                                                              \
        {                                                                              \
            float16v acc;                                                              \
            _Pragma("unroll")                                                          \
            for (int ar = 0; ar < 4; ++ar) {                                           \
                const float4 bv = *(const float4*)(sB + sB2 + c * 64 + (CT2) * 32 + ar * 8 + q2 * 4); \
                acc[4 * ar + 0] = bv.x; acc[4 * ar + 1] = bv.y;                        \
                acc[4 * ar + 2] = bv.z; acc[4 * ar + 3] = bv.w;                        \
            }                                                                          \
            _Pragma("unroll")                                                          \
            for (int kb = 0; kb < 8; ++kb) {                                           \
                uint32_t x0 = pk1[2 * kb][0], y0 = pk1[2 * kb + 1][0];                 \
                uint32_t x1 = pk1[2 * kb][1], y1 = pk1[2 * kb + 1][1];                 \
                plane32swap(x0, y0);                                                   \
                plane32swap(x1, y1);                                                   \
                Frag Hf; Hf.u[0] = x0; Hf.u[1] = x1; Hf.u[2] = y0; Hf.u[3] = y1;       \
                acc = __builtin_amdgcn_mfma_f32_32x32x16_bf16(F2R[kb].s8, Hf.s8, acc, 0, 0, 0); \
            }                                                                          \
            _Pragma("unroll")                                                          \
            for (int ar = 0; ar < 4; ++ar) {                                           \
                pk2[(CT2) * 4 + ar][0] = cvtpk_bf16(siluf(acc[4 * ar + 0]),            \
                                                    siluf(acc[4 * ar + 1]));           \
                pk2[(CT2) * 4 + ar][1] = cvtpk_bf16(siluf(acc[4 * ar + 2]),            \
                                                    siluf(acc[4 * ar + 3]));           \
            }                                                                          \
        }
        L2_TILE(F2a, 0)
        L2_TILE(F2b, 1)
#undef L2_TILE

        // ===== L3: H3^T = W3 . H2^T   (1 col-tile of 32, K=64; F3 from LDS) =====
        {
            float16v acc;
#pragma unroll
            for (int ar = 0; ar < 4; ++ar) {           // bias-fold: C-in = b3
                const float4 bv = *(const float4*)(sB + sB3 + c * 32 + ar * 8 + q2 * 4);
                acc[4 * ar + 0] = bv.x; acc[4 * ar + 1] = bv.y;
                acc[4 * ar + 2] = bv.z; acc[4 * ar + 3] = bv.w;
            }
#pragma unroll
            for (int kb = 0; kb < 4; ++kb) {
                uint32_t x0 = pk2[2 * kb][0], y0 = pk2[2 * kb + 1][0];
                uint32_t x1 = pk2[2 * kb][1], y1 = pk2[2 * kb + 1][1];
                plane32swap(x0, y0);
                plane32swap(x1, y1);
                Frag Hf; Hf.u[0] = x0; Hf.u[1] = x1; Hf.u[2] = y0; Hf.u[3] = y1;
                Frag Af; Af.u4 = *(const uint4*)(sW + sWF3 + (kb * 64 + l) * 8);
                acc = __builtin_amdgcn_mfma_f32_32x32x16_bf16(Af.s8, Hf.s8, acc, 0, 0, 0);
            }
            // ===== L4: raw[r=l5] = silu(H3).W4 + b4, reduce over q2 =====
            float part = 0.f;
#pragma unroll
            for (int ar = 0; ar < 4; ++ar) {
                const float4 wv = *(const float4*)(sB + sW4 + c * 32 + ar * 8 + q2 * 4);
                part = fmaf(siluf(acc[4 * ar + 0]), wv.x, part);
                part = fmaf(siluf(acc[4 * ar + 1]), wv.y, part);
                part = fmaf(siluf(acc[4 * ar + 2]), wv.z, part);
                part = fmaf(siluf(acc[4 * ar + 3]), wv.w, part);
            }
            part += __shfl_xor(part, 32);
            const float rv = part + sB[sB4 + c];
            raw0 = (c == 0) ? rv : raw0;
            raw1 = (c == 1) ? rv : raw1;
            raw2 = (c == 2) ? rv : raw2;
            raw3 = (c == 3) ? rv : raw3;
            raw4 = (c == 4) ? rv : raw4;
            raw5 = (c == 5) ? rv : raw5;
        }
    }

    // ===== Coupling fixed point (redundant over q2; static indexing) =====
    const float rv6[6] = {raw0, raw1, raw2, raw3, raw4, raw5};
    float av[6];
#pragma unroll
    for (int c = 0; c < 6; ++c) av[c] = sigmoidf_fast(rv6[c]);
    const float K = 0.02f;
#pragma unroll 1
    for (int it = 0; it < 5; ++it) {
        float tt[6];
#pragma unroll
        for (int i = 0; i < 6; ++i) tt[i] = av[i] * sB[sDC + i] * K;
#pragma unroll
        for (int j = 0; j < 6; ++j) {
            float dl = 0.0f;
#pragma unroll
            for (int i = 0; i < 6; ++i) dl = fmaf(tt[i], sB[sCP + i * 6 + j], dl);
            av[j] = sigmoidf_fast(rv6[j] + dl);
        }
    }
    if (q2 == 0) {
        float2* oa = (float2*)(outF + (size_t)row * 6);
        oa[0] = make_float2(av[0], av[1]);
        oa[1] = make_float2(av[2], av[3]);
        oa[2] = make_float2(av[4], av[5]);
        float2* orw = (float2*)(outF + (size_t)B_TOTAL * 6 + (size_t)row * 6);
        orw[0] = make_float2(rv6[0], rv6[1]);
        orw[1] = make_float2(rv6[2], rv6[3]);
        orw[2] = make_float2(rv6[4], rv6[5]);
    }
}

extern "C" void kernel_launch(void* const* d_in, const int* in_sizes, int n_in,
                              void* d_out, int out_size, void* d_ws, size_t ws_size,
                              hipStream_t stream) {
    uint16_t* wsb = (uint16_t*)d_ws;
    convert_kernel<<<(CONV_TOT + 255) / 256, 256, 0, stream>>>(
        d_in[1], d_in[2], d_in[3], d_in[4], d_in[5], d_in[6], d_in[7], d_in[8],
        d_in[9], d_in[10], wsb);
    chambers_mfma<<<B_TOTAL / 256, 512, 0, stream>>>(
        d_in[0], wsb, (const uint32_t*)d_in[9], (float*)d_out);
}